// Round 2
// baseline (15299.142 us; speedup 1.0000x reference)
//
#include <hip/hip_runtime.h>
#include <hip/hip_bf16.h>

typedef unsigned short u16;
typedef _Float16 f16;
typedef _Float16 f16x2 __attribute__((ext_vector_type(2)));
typedef _Float16 f16x8 __attribute__((ext_vector_type(8)));
typedef short s8v __attribute__((ext_vector_type(8)));
typedef float f4v __attribute__((ext_vector_type(4)));

#define RK 48   // register-resident k2 pairs (of 128) in LSTM
#define SK 20   // streamed chunks of 4 pairs: 48 + 20*4 = 128

__device__ __forceinline__ u16 f2bf(float f) {
    union { float f; unsigned u; } v; v.f = f;
    unsigned r = v.u + 0x7FFF + ((v.u >> 16) & 1);
    return (u16)(r >> 16);
}
__device__ __forceinline__ u16 f2h(float f) {
    f16 h = (f16)f;
    union { f16 h; u16 u; } v; v.h = h;
    return v.u;
}
__device__ __forceinline__ f16x2 pair_of(f16x8 v, int i) {
    union { f16x8 v8; f16x2 p[4]; } u; u.v8 = v;
    return u.p[i];
}
__device__ __forceinline__ float fdot2(f16x2 a, f16x2 b, float c) {
#if defined(__has_builtin) && __has_builtin(__builtin_amdgcn_fdot2)
    return __builtin_amdgcn_fdot2(a, b, c, false);
#else
    return c + (float)a.x * (float)b.x + (float)a.y * (float)b.y;
#endif
}
__device__ __forceinline__ float sigm(float x) { return 1.f / (1.f + __expf(-x)); }

// ---------------------------------------------------------------------------
// Weight prep: transposes to [N][K] bf16 for MFMA B-operand, packs Ul to f16
// pair layout for the LSTM (reg part + streamed part).
// ---------------------------------------------------------------------------
__global__ __launch_bounds__(256) void prep_kernel(
    const float* __restrict__ Wx, const float* __restrict__ Wc,
    const float* __restrict__ Wl, const float* __restrict__ Wo,
    const float* __restrict__ Ul,
    u16* __restrict__ wxT, u16* __restrict__ wcT, u16* __restrict__ wlT,
    u16* __restrict__ woT, f16x2* __restrict__ ull)
{
    int i = blockIdx.x * 256 + threadIdx.x;
    if (i < 65536) {                    // WxT[n][k] : 128x512
        int n = i >> 9, k = i & 511;
        wxT[i] = f2bf(Wx[k * 128 + n]);
    } else if (i < 131072) {            // WcT
        int t = i - 65536;
        int n = t >> 9, k = t & 511;
        wcT[t] = f2bf(Wc[k * 128 + n]);
    } else if (i < 425984) {            // WlT[n][k] : 1024x288 (K padded 257->288)
        int t = i - 131072;
        int n = t / 288, k = t % 288;
        wlT[t] = (k < 257) ? f2bf(Wl[k * 1024 + n]) : (u16)0;
    } else if (i < 491520) {            // WoT[n][k] : 256x256
        int t = i - 425984;
        int n = t >> 8, k = t & 255;
        woT[t] = f2bf(Wo[k * 256 + n]);
    } else if (i < 622592) {            // Ul packed f16 pairs: 131072 pairs
        int t = i - 491520;
        int k2, col;
        int outi;
        if (t < 4 * RK * 256) {         // register part: [(g*RK+k2)*256 + j]
            int j = t & 255, r = t >> 8;
            k2 = r % RK; int g = r / RK;
            col = g * 256 + j;
            outi = t;
        } else {                         // stream part: [((g*SK+kc)*256+j)*4 + p]
            int t2 = t - 4 * RK * 256;
            int p = t2 & 3, j = (t2 >> 2) & 255, r = t2 >> 10;
            int kc = r % SK, g = r / SK;
            k2 = RK + kc * 4 + p;
            col = g * 256 + j;
            outi = t;
        }
        f16x2 v;
        v.x = (f16)Ul[(2 * k2) * 1024 + col];
        v.y = (f16)Ul[(2 * k2 + 1) * 1024 + col];
        ull[outi] = v;
    }
}

// ---------------------------------------------------------------------------
// s[b,t] = sum_k x[b,t,k]   (one wave per row)
// ---------------------------------------------------------------------------
__global__ __launch_bounds__(256) void row_sums(const float4* __restrict__ x4,
                                                float* __restrict__ s)
{
    int w = threadIdx.x >> 6, lane = threadIdx.x & 63;
    size_t row = (size_t)blockIdx.x * 4 + w;
    const float4* r = x4 + row * 128;
    float4 a = r[lane], b = r[64 + lane];
    float sum = a.x + a.y + a.z + a.w + b.x + b.y + b.z + b.w;
    #pragma unroll
    for (int d = 32; d >= 1; d >>= 1) sum += __shfl_xor(sum, d);
    if (lane == 0) s[row] = sum;
}

// ---------------------------------------------------------------------------
// Count recurrence c_t = s_t*c_{t-1} + x_t; writes log1p(c) and x as bf16.
// One block per batch; lane = feature k. Chunked loads to hide HBM latency.
// ---------------------------------------------------------------------------
__global__ __launch_bounds__(512) void count_scan(const float* __restrict__ x,
                                                  const float* __restrict__ s,
                                                  u16* __restrict__ xbf,
                                                  u16* __restrict__ clog)
{
    int k = threadIdx.x, b = blockIdx.x;
    const float* xb = x + (size_t)b * 1024 * 512;
    const float* sb = s + (size_t)b * 1024;
    u16* xo = xbf + (size_t)b * 1024 * 512;
    u16* co = clog + (size_t)b * 1024 * 512;
    float c = 0.f;
    for (int t0 = 0; t0 < 1024; t0 += 8) {
        float xv[8], sv[8];
        #pragma unroll
        for (int i = 0; i < 8; ++i) {
            xv[i] = xb[(size_t)(t0 + i) * 512 + k];
            sv[i] = sb[t0 + i];
        }
        #pragma unroll
        for (int i = 0; i < 8; ++i) {
            c = sv[i] * c + xv[i];
            size_t idx = (size_t)(t0 + i) * 512 + k;
            xo[idx] = f2bf(xv[i]);
            co[idx] = f2bf(log1pf(c));
        }
    }
}

// ---------------------------------------------------------------------------
// xc[:,256] = exp(-(delta*Wd+bd)); xc[:,257:288] = 0
// ---------------------------------------------------------------------------
__global__ __launch_bounds__(256) void fill_xc(const float* __restrict__ delta,
                                               const float* __restrict__ Wd,
                                               const float* __restrict__ bd,
                                               u16* __restrict__ xc)
{
    int i = blockIdx.x * 256 + threadIdx.x;   // 65536*32
    int row = i >> 5, cc = i & 31;
    float v = 0.f;
    if (cc == 0) v = __expf(-(delta[row] * Wd[0] + bd[0]));
    xc[(size_t)row * 288 + 256 + cc] = f2bf(v);
}

// ---------------------------------------------------------------------------
// Generic 128x128-tile bf16 MFMA GEMM: C[row, colofs+col] = A@B + bias.
// A: [M,K] bf16 row-major, BT: [N,K] bf16 (i.e. B transposed), K % 32 == 0.
// EPI 0 -> bf16 out, EPI 1 -> f16 out.
// ---------------------------------------------------------------------------
template <int EPI>
__global__ __launch_bounds__(256) void gemm128(const u16* __restrict__ A,
                                               const u16* __restrict__ BT,
                                               const float* __restrict__ bias,
                                               u16* __restrict__ C,
                                               int K, int ldc, int colofs)
{
    __shared__ u16 Alds[128 * 40];
    __shared__ u16 Blds[128 * 40];
    int tid = threadIdx.x;
    int m0 = blockIdx.x * 128, n0 = blockIdx.y * 128;
    int lane = tid & 63, w = tid >> 6, quad = lane >> 4, m16 = lane & 15;
    int wm = w & 1, wn = w >> 1;
    f4v acc[4][4];
    #pragma unroll
    for (int i = 0; i < 4; ++i)
        #pragma unroll
        for (int j = 0; j < 4; ++j) acc[i][j] = (f4v){0.f, 0.f, 0.f, 0.f};

    for (int k0 = 0; k0 < K; k0 += 32) {
        #pragma unroll
        for (int p = 0; p < 2; ++p) {
            int e = (p * 256 + tid) * 8;
            int r = e >> 5, cc = e & 31;
            *(uint4*)&Alds[r * 40 + cc] =
                *(const uint4*)&A[(size_t)(m0 + r) * K + k0 + cc];
            *(uint4*)&Blds[r * 40 + cc] =
                *(const uint4*)&BT[(size_t)(n0 + r) * K + k0 + cc];
        }
        __syncthreads();
        s8v af[4], bf[4];
        #pragma unroll
        for (int i = 0; i < 4; ++i)
            af[i] = *(const s8v*)&Alds[(wm * 64 + i * 16 + m16) * 40 + quad * 8];
        #pragma unroll
        for (int i = 0; i < 4; ++i)
            bf[i] = *(const s8v*)&Blds[(wn * 64 + i * 16 + m16) * 40 + quad * 8];
        #pragma unroll
        for (int i = 0; i < 4; ++i)
            #pragma unroll
            for (int nj = 0; nj < 4; ++nj)
                acc[i][nj] = __builtin_amdgcn_mfma_f32_16x16x32_bf16(
                    af[i], bf[nj], acc[i][nj], 0, 0, 0);
        __syncthreads();
    }
    #pragma unroll
    for (int nj = 0; nj < 4; ++nj) {
        int col = n0 + wn * 64 + nj * 16 + m16;
        float bv = bias[col];
        #pragma unroll
        for (int i = 0; i < 4; ++i)
            #pragma unroll
            for (int r = 0; r < 4; ++r) {
                int row = m0 + wm * 64 + i * 16 + quad * 4 + r;
                float v = acc[i][nj][r] + bv;
                C[(size_t)row * ldc + colofs + col] = (EPI == 0) ? f2bf(v) : f2h(v);
            }
    }
}

// ---------------------------------------------------------------------------
// LSTM over T=1024. One block per batch, 256 threads (4 waves, 1 wave/SIMD,
// 512-VGPR budget). Thread j owns h-col j and Ul columns {j,256+j,512+j,768+j}.
// 48/128 k-pairs of Ul live in registers; 80 streamed from L2 each step.
// h broadcast through LDS into registers each step. f16 matvec, fp32 cell.
// ---------------------------------------------------------------------------
__global__ __launch_bounds__(256, 1) void lstm_kernel(const f16* __restrict__ pre,
                                                      const f16x2* __restrict__ ull,
                                                      u16* __restrict__ hout)
{
    int j = threadIdx.x, b = blockIdx.x;
    __shared__ __align__(16) f16 hsh[2][256];

    f16x2 ulr[4][RK];
    #pragma unroll
    for (int g = 0; g < 4; ++g)
        #pragma unroll
        for (int k = 0; k < RK; ++k) ulr[g][k] = ull[(g * RK + k) * 256 + j];
    const f16x8* uls = (const f16x8*)(ull + 4 * RK * 256);

    hsh[0][j] = (f16)0.f;
    float c = 0.f;
    const f16* prep = pre + (size_t)b * 1024 * 1024;
    u16* ho = hout + (size_t)b * 1024 * 256;
    __syncthreads();

    float pcur[4], pnext[4];
    #pragma unroll
    for (int g = 0; g < 4; ++g) pcur[g] = (float)prep[g * 256 + j];

    for (int t = 0; t < 1024; ++t) {
        int tn = (t + 1 < 1024) ? (t + 1) : 1023;
        const f16* pn = prep + (size_t)tn * 1024;
        #pragma unroll
        for (int g = 0; g < 4; ++g) pnext[g] = (float)pn[g * 256 + j];

        // broadcast h into registers (32 x b128 same-address LDS reads)
        f16x8 hreg8[32];
        #pragma unroll
        for (int r = 0; r < 32; ++r)
            hreg8[r] = ((const f16x8*)&hsh[t & 1][0])[r];

        float z0 = pcur[0], z1 = pcur[1], z2 = pcur[2], z3 = pcur[3];
        // register-resident part
        #pragma unroll
        for (int k = 0; k < RK; ++k) {
            f16x2 hp = pair_of(hreg8[k >> 2], k & 3);
            z0 = fdot2(hp, ulr[0][k], z0);
            z1 = fdot2(hp, ulr[1][k], z1);
            z2 = fdot2(hp, ulr[2][k], z2);
            z3 = fdot2(hp, ulr[3][k], z3);
        }
        // streamed part (L2-resident Ul)
        #pragma unroll
        for (int kc = 0; kc < SK; ++kc) {
            f16x8 u0 = uls[(0 * SK + kc) * 256 + j];
            f16x8 u1 = uls[(1 * SK + kc) * 256 + j];
            f16x8 u2 = uls[(2 * SK + kc) * 256 + j];
            f16x8 u3 = uls[(3 * SK + kc) * 256 + j];
            #pragma unroll
            for (int p = 0; p < 4; ++p) {
                int k = RK + kc * 4 + p;
                f16x2 hp = pair_of(hreg8[k >> 2], k & 3);
                z0 = fdot2(hp, pair_of(u0, p), z0);
                z1 = fdot2(hp, pair_of(u1, p), z1);
                z2 = fdot2(hp, pair_of(u2, p), z2);
                z3 = fdot2(hp, pair_of(u3, p), z3);
            }
        }
        float ig = sigm(z0);
        float fg = sigm(z1);
        float gg = tanhf(z2);
        float og = sigm(z3);
        c = fg * c + ig * gg;
        float h = og * tanhf(c);
        hsh[(t + 1) & 1][j] = (f16)h;
        ho[(size_t)t * 256 + j] = f2bf(h);
        #pragma unroll
        for (int g = 0; g < 4; ++g) pcur[g] = pnext[g];
        __syncthreads();
    }
}

// ---------------------------------------------------------------------------
// out[row] = sum_n sigmoid(h[row]@Wo[:,n] + bo[n]) * q[row,n]
// Block covers 64 rows x full N=256 (wave w -> cols [w*64, w*64+64)).
// ---------------------------------------------------------------------------
__global__ __launch_bounds__(256) void gemm_out(const u16* __restrict__ H,
                                                const u16* __restrict__ woT,
                                                const float* __restrict__ bo,
                                                const float* __restrict__ q,
                                                float* __restrict__ out)
{
    __shared__ u16 Alds[64 * 40];
    __shared__ u16 Blds[256 * 40];
    __shared__ float red[64][4];
    int tid = threadIdx.x;
    int m0 = blockIdx.x * 64;
    int lane = tid & 63, w = tid >> 6, quad = lane >> 4, m16 = lane & 15;
    f4v acc[4][4];
    #pragma unroll
    for (int i = 0; i < 4; ++i)
        #pragma unroll
        for (int j = 0; j < 4; ++j) acc[i][j] = (f4v){0.f, 0.f, 0.f, 0.f};

    for (int k0 = 0; k0 < 256; k0 += 32) {
        {
            int e = tid * 8;
            int r = e >> 5, cc = e & 31;
            *(uint4*)&Alds[r * 40 + cc] =
                *(const uint4*)&H[(size_t)(m0 + r) * 256 + k0 + cc];
        }
        #pragma unroll
        for (int p = 0; p < 4; ++p) {
            int e = (p * 256 + tid) * 8;
            int r = e >> 5, cc = e & 31;
            *(uint4*)&Blds[r * 40 + cc] =
                *(const uint4*)&woT[(size_t)r * 256 + k0 + cc];
        }
        __syncthreads();
        s8v af[4], bf[4];
        #pragma unroll
        for (int i = 0; i < 4; ++i)
            af[i] = *(const s8v*)&Alds[(i * 16 + m16) * 40 + quad * 8];
        #pragma unroll
        for (int i = 0; i < 4; ++i)
            bf[i] = *(const s8v*)&Blds[(w * 64 + i * 16 + m16) * 40 + quad * 8];
        #pragma unroll
        for (int i = 0; i < 4; ++i)
            #pragma unroll
            for (int nj = 0; nj < 4; ++nj)
                acc[i][nj] = __builtin_amdgcn_mfma_f32_16x16x32_bf16(
                    af[i], bf[nj], acc[i][nj], 0, 0, 0);
        __syncthreads();
    }
    float rsum[4][4];
    #pragma unroll
    for (int i = 0; i < 4; ++i)
        #pragma unroll
        for (int r = 0; r < 4; ++r) rsum[i][r] = 0.f;
    #pragma unroll
    for (int nj = 0; nj < 4; ++nj) {
        int col = w * 64 + nj * 16 + m16;
        float bv = bo[col];
        #pragma unroll
        for (int i = 0; i < 4; ++i)
            #pragma unroll
            for (int r = 0; r < 4; ++r) {
                int row = m0 + i * 16 + quad * 4 + r;
                float v = sigm(acc[i][nj][r] + bv);
                rsum[i][r] += v * q[(size_t)row * 256 + col];
            }
    }
    #pragma unroll
    for (int d = 1; d <= 8; d <<= 1)
        #pragma unroll
        for (int i = 0; i < 4; ++i)
            #pragma unroll
            for (int r = 0; r < 4; ++r) rsum[i][r] += __shfl_xor(rsum[i][r], d);
    if (m16 == 0) {
        #pragma unroll
        for (int i = 0; i < 4; ++i)
            #pragma unroll
            for (int r = 0; r < 4; ++r)
                red[i * 16 + quad * 4 + r][w] = rsum[i][r];
    }
    __syncthreads();
    if (tid < 64)
        out[m0 + tid] = red[tid][0] + red[tid][1] + red[tid][2] + red[tid][3];
}

// ---------------------------------------------------------------------------
extern "C" void kernel_launch(void* const* d_in, const int* in_sizes, int n_in,
                              void* d_out, int out_size, void* d_ws, size_t ws_size,
                              hipStream_t stream)
{
    (void)in_sizes; (void)n_in; (void)out_size; (void)ws_size;
    const float* x     = (const float*)d_in[0];
    const float* delta = (const float*)d_in[1];
    const float* q     = (const float*)d_in[2];
    const float* Wx    = (const float*)d_in[3];
    const float* bx    = (const float*)d_in[4];
    const float* Wc    = (const float*)d_in[5];
    const float* bc    = (const float*)d_in[6];
    const float* Wd    = (const float*)d_in[7];
    const float* bd    = (const float*)d_in[8];
    const float* Wl    = (const float*)d_in[9];
    const float* Ul    = (const float*)d_in[10];
    const float* bl    = (const float*)d_in[11];
    const float* Wo    = (const float*)d_in[12];
    const float* bo    = (const float*)d_in[13];

    char* ws = (char*)d_ws;
    float* s_buf = (float*)(ws + 0);            // 256 KB
    f16x2* ull   = (f16x2*)(ws + 262144);       // 512 KB
    u16* wxT     = (u16*)(ws + 786432);         // 128 KB
    u16* wcT     = (u16*)(ws + 917504);         // 128 KB
    u16* wlT     = (u16*)(ws + 1048576);        // 576 KB
    u16* woT     = (u16*)(ws + 1638400);        // 128 KB
    u16* xc      = (u16*)(ws + 1769472);        // 36 MB  [65536 x 288] bf16
    u16* hbuf    = (u16*)(ws + 39518208);       // 32 MB  [65536 x 256] bf16
    u16* xbf     = (u16*)(ws + 73072640);       // 64 MB  bf16 copy of x
    u16* clog    = (u16*)(ws + 140181504);      // 64 MB  log1p(counts) bf16
    f16* pre     = (f16*)(ws + 73072640);       // 128 MB f16, aliases xbf+clog

    prep_kernel<<<2432, 256, 0, stream>>>(Wx, Wc, Wl, Wo, Ul, wxT, wcT, wlT, woT, ull);
    row_sums<<<16384, 256, 0, stream>>>((const float4*)x, s_buf);
    count_scan<<<64, 512, 0, stream>>>(x, s_buf, xbf, clog);
    fill_xc<<<8192, 256, 0, stream>>>(delta, Wd, bd, xc);
    gemm128<0><<<dim3(512, 1), 256, 0, stream>>>(xbf, wxT, bx, xc, 512, 288, 0);
    gemm128<0><<<dim3(512, 1), 256, 0, stream>>>(clog, wcT, bc, xc, 512, 288, 128);
    gemm128<1><<<dim3(512, 8), 256, 0, stream>>>(xc, wlT, bl, (u16*)pre, 288, 1024, 0);
    lstm_kernel<<<64, 256, 0, stream>>>(pre, ull, hbuf);
    gemm_out<<<1024, 256, 0, stream>>>(hbuf, woT, bo, q, (float*)d_out);
}

// Round 3
// 3403.991 us; speedup vs baseline: 4.4945x; 4.4945x over previous
//
#include <hip/hip_runtime.h>
#include <hip/hip_bf16.h>

typedef unsigned short u16;
typedef _Float16 f16;
typedef _Float16 f16x2 __attribute__((ext_vector_type(2)));
typedef _Float16 f16x8 __attribute__((ext_vector_type(8)));
typedef short s8v __attribute__((ext_vector_type(8)));
typedef float f4v __attribute__((ext_vector_type(4)));

// LSTM Ul residency split (128 k-pairs total): VGPR + AGPR + LDS = all resident
#define RKV 40                        // pairs in VGPRs (4 gates x 40 = 160 regs)
#define RKA 64                        // pairs in AGPRs (4 x 64 = 256 AGPRs)
#define RKL 24                        // pairs in LDS   (96 KB)
#define AOFF (4 * RKV * 256)          // 40960 pairs
#define LOFF (AOFF + 4 * RKA * 256)   // 106496 pairs
#define WLDS_BYTES ((RKL / 4) * 4 * 256 * 16)   // 98304
#define LSTM_SMEM (WLDS_BYTES + 2 * 256 * 2)    // + h double buffer = 99328

__device__ __forceinline__ u16 f2bf(float f) {
    union { float f; unsigned u; } v; v.f = f;
    unsigned r = v.u + 0x7FFF + ((v.u >> 16) & 1);
    return (u16)(r >> 16);
}
__device__ __forceinline__ u16 f2h(float f) {
    f16 h = (f16)f;
    union { f16 h; u16 u; } v; v.h = h;
    return v.u;
}
__device__ __forceinline__ f16x2 pair_of(f16x8 v, int i) {
    union { f16x8 v8; f16x2 p[4]; } u; u.v8 = v;
    return u.p[i];
}
__device__ __forceinline__ float fdot2(f16x2 a, f16x2 b, float c) {
#if defined(__has_builtin) && __has_builtin(__builtin_amdgcn_fdot2)
    return __builtin_amdgcn_fdot2(a, b, c, false);
#else
    return c + (float)a.x * (float)b.x + (float)a.y * (float)b.y;
#endif
}
__device__ __forceinline__ float sigm(float x) { return 1.f / (1.f + __expf(-x)); }
__device__ __forceinline__ float fast_tanh(float x) {
    float ax = fabsf(x);
    float e = __expf(2.f * ax);
    float r = 1.f - 2.f / (e + 1.f);   // overflow-safe: e=inf -> r=1
    return copysignf(r, x);
}
__device__ __forceinline__ f16x2 aread(const float& a) {
    union { float f; f16x2 p; } u;
    asm volatile("v_accvgpr_read_b32 %0, %1" : "=v"(u.f) : "a"(a));
    return u.p;
}

// ---------------------------------------------------------------------------
// Weight prep: transposes to [N][K] bf16 for MFMA B-operand, packs Ul to f16
// pair layout for the LSTM: VGPR region / AGPR region / LDS region.
// ---------------------------------------------------------------------------
__global__ __launch_bounds__(256) void prep_kernel(
    const float* __restrict__ Wx, const float* __restrict__ Wc,
    const float* __restrict__ Wl, const float* __restrict__ Wo,
    const float* __restrict__ Ul,
    u16* __restrict__ wxT, u16* __restrict__ wcT, u16* __restrict__ wlT,
    u16* __restrict__ woT, f16x2* __restrict__ ull)
{
    int i = blockIdx.x * 256 + threadIdx.x;
    if (i < 65536) {                    // WxT[n][k] : 128x512
        int n = i >> 9, k = i & 511;
        wxT[i] = f2bf(Wx[k * 128 + n]);
    } else if (i < 131072) {            // WcT
        int t = i - 65536;
        int n = t >> 9, k = t & 511;
        wcT[t] = f2bf(Wc[k * 128 + n]);
    } else if (i < 425984) {            // WlT[n][k] : 1024x288 (K padded 257->288)
        int t = i - 131072;
        int n = t / 288, k = t % 288;
        wlT[t] = (k < 257) ? f2bf(Wl[k * 1024 + n]) : (u16)0;
    } else if (i < 491520) {            // WoT[n][k] : 256x256
        int t = i - 425984;
        int n = t >> 8, k = t & 255;
        woT[t] = f2bf(Wo[k * 256 + n]);
    } else if (i < 622592) {            // Ul packed f16 pairs: 131072 pairs
        int t = i - 491520;
        int j = t & 255;
        int r = t >> 8;                 // [0,512)
        int k2 = r & 127;               // global pair index
        int g = r >> 7;                 // gate
        int outi;
        if (k2 < RKV) {
            outi = (g * RKV + k2) * 256 + j;
        } else if (k2 < RKV + RKA) {
            outi = AOFF + (g * RKA + (k2 - RKV)) * 256 + j;
        } else {
            int kl = k2 - RKV - RKA;    // [0,RKL)
            int kc = kl >> 2, p = kl & 3;
            outi = LOFF + ((kc * 4 + g) * 256 + j) * 4 + p;
        }
        int col = g * 256 + j;
        f16x2 v;
        v.x = (f16)Ul[(2 * k2) * 1024 + col];
        v.y = (f16)Ul[(2 * k2 + 1) * 1024 + col];
        ull[outi] = v;
    }
}

// ---------------------------------------------------------------------------
// s[b,t] = sum_k x[b,t,k]   (one wave per row)
// ---------------------------------------------------------------------------
__global__ __launch_bounds__(256) void row_sums(const float4* __restrict__ x4,
                                                float* __restrict__ s)
{
    int w = threadIdx.x >> 6, lane = threadIdx.x & 63;
    size_t row = (size_t)blockIdx.x * 4 + w;
    const float4* r = x4 + row * 128;
    float4 a = r[lane], b = r[64 + lane];
    float sum = a.x + a.y + a.z + a.w + b.x + b.y + b.z + b.w;
    #pragma unroll
    for (int d = 32; d >= 1; d >>= 1) sum += __shfl_xor(sum, d);
    if (lane == 0) s[row] = sum;
}

// ---------------------------------------------------------------------------
// Count recurrence c_t = s_t*c_{t-1} + x_t; writes log1p(c) and x as bf16.
// ---------------------------------------------------------------------------
__global__ __launch_bounds__(512) void count_scan(const float* __restrict__ x,
                                                  const float* __restrict__ s,
                                                  u16* __restrict__ xbf,
                                                  u16* __restrict__ clog)
{
    int k = threadIdx.x, b = blockIdx.x;
    const float* xb = x + (size_t)b * 1024 * 512;
    const float* sb = s + (size_t)b * 1024;
    u16* xo = xbf + (size_t)b * 1024 * 512;
    u16* co = clog + (size_t)b * 1024 * 512;
    float c = 0.f;
    for (int t0 = 0; t0 < 1024; t0 += 8) {
        float xv[8], sv[8];
        #pragma unroll
        for (int i = 0; i < 8; ++i) {
            xv[i] = xb[(size_t)(t0 + i) * 512 + k];
            sv[i] = sb[t0 + i];
        }
        #pragma unroll
        for (int i = 0; i < 8; ++i) {
            c = sv[i] * c + xv[i];
            size_t idx = (size_t)(t0 + i) * 512 + k;
            xo[idx] = f2bf(xv[i]);
            co[idx] = f2bf(log1pf(c));
        }
    }
}

// ---------------------------------------------------------------------------
// xc[:,256] = exp(-(delta*Wd+bd)); xc[:,257:288] = 0
// ---------------------------------------------------------------------------
__global__ __launch_bounds__(256) void fill_xc(const float* __restrict__ delta,
                                               const float* __restrict__ Wd,
                                               const float* __restrict__ bd,
                                               u16* __restrict__ xc)
{
    int i = blockIdx.x * 256 + threadIdx.x;   // 65536*32
    int row = i >> 5, cc = i & 31;
    float v = 0.f;
    if (cc == 0) v = __expf(-(delta[row] * Wd[0] + bd[0]));
    xc[(size_t)row * 288 + 256 + cc] = f2bf(v);
}

// ---------------------------------------------------------------------------
// Generic 128x128-tile bf16 MFMA GEMM: C[row, colofs+col] = A@B + bias.
// ---------------------------------------------------------------------------
template <int EPI>
__global__ __launch_bounds__(256) void gemm128(const u16* __restrict__ A,
                                               const u16* __restrict__ BT,
                                               const float* __restrict__ bias,
                                               u16* __restrict__ C,
                                               int K, int ldc, int colofs)
{
    __shared__ u16 Alds[128 * 40];
    __shared__ u16 Blds[128 * 40];
    int tid = threadIdx.x;
    int m0 = blockIdx.x * 128, n0 = blockIdx.y * 128;
    int lane = tid & 63, w = tid >> 6, quad = lane >> 4, m16 = lane & 15;
    int wm = w & 1, wn = w >> 1;
    f4v acc[4][4];
    #pragma unroll
    for (int i = 0; i < 4; ++i)
        #pragma unroll
        for (int j = 0; j < 4; ++j) acc[i][j] = (f4v){0.f, 0.f, 0.f, 0.f};

    for (int k0 = 0; k0 < K; k0 += 32) {
        #pragma unroll
        for (int p = 0; p < 2; ++p) {
            int e = (p * 256 + tid) * 8;
            int r = e >> 5, cc = e & 31;
            *(uint4*)&Alds[r * 40 + cc] =
                *(const uint4*)&A[(size_t)(m0 + r) * K + k0 + cc];
            *(uint4*)&Blds[r * 40 + cc] =
                *(const uint4*)&BT[(size_t)(n0 + r) * K + k0 + cc];
        }
        __syncthreads();
        s8v af[4], bf[4];
        #pragma unroll
        for (int i = 0; i < 4; ++i)
            af[i] = *(const s8v*)&Alds[(wm * 64 + i * 16 + m16) * 40 + quad * 8];
        #pragma unroll
        for (int i = 0; i < 4; ++i)
            bf[i] = *(const s8v*)&Blds[(wn * 64 + i * 16 + m16) * 40 + quad * 8];
        #pragma unroll
        for (int i = 0; i < 4; ++i)
            #pragma unroll
            for (int nj = 0; nj < 4; ++nj)
                acc[i][nj] = __builtin_amdgcn_mfma_f32_16x16x32_bf16(
                    af[i], bf[nj], acc[i][nj], 0, 0, 0);
        __syncthreads();
    }
    #pragma unroll
    for (int nj = 0; nj < 4; ++nj) {
        int col = n0 + wn * 64 + nj * 16 + m16;
        float bv = bias[col];
        #pragma unroll
        for (int i = 0; i < 4; ++i)
            #pragma unroll
            for (int r = 0; r < 4; ++r) {
                int row = m0 + wm * 64 + i * 16 + quad * 4 + r;
                float v = acc[i][nj][r] + bv;
                C[(size_t)row * ldc + colofs + col] = (EPI == 0) ? f2bf(v) : f2h(v);
            }
    }
}

// ---------------------------------------------------------------------------
// LSTM over T=1024. One block per batch, 256 threads, 1 wave/SIMD.
// Ul fully CU-resident: 40 pairs VGPR + 64 pairs AGPR + 24 pairs LDS.
// h double-buffered in LDS, read into 32-reg quarters. Zero per-step
// global weight traffic.
// ---------------------------------------------------------------------------
__global__ __launch_bounds__(256, 1) void lstm_kernel(const f16* __restrict__ pre,
                                                      const f16x2* __restrict__ ull,
                                                      u16* __restrict__ hout)
{
    extern __shared__ char smem[];
    f16x8* wlds = (f16x8*)smem;                       // [(kc*4+g)*256 + j]
    f16* hsh = (f16*)(smem + WLDS_BYTES);             // [2][256]
    int j = threadIdx.x, b = blockIdx.x;

    // stage LDS-resident weights (once)
    const f16x8* wl = (const f16x8*)(ull + LOFF);
    #pragma unroll
    for (int i = 0; i < RKL; ++i)                     // 24 chunks of f16x8
        wlds[i * 256 + j] = wl[i * 256 + j];

    // VGPR-resident weights
    f16x2 ulr[4][RKV];
    #pragma unroll
    for (int g = 0; g < 4; ++g)
        #pragma unroll
        for (int k = 0; k < RKV; ++k)
            ulr[g][k] = ull[(g * RKV + k) * 256 + j];

    // AGPR-resident weights
    float agv[4 * RKA];
    {
        const f16x2* ua = ull + AOFF;
        #pragma unroll
        for (int i = 0; i < 4 * RKA; ++i) {
            union { f16x2 p; float f; } u;
            u.p = ua[i * 256 + j];
            asm volatile("v_accvgpr_write_b32 %0, %1" : "=a"(agv[i]) : "v"(u.f));
        }
    }

    float c = 0.f;
    hsh[j] = (f16)0.f;
    const f16* prep_ = pre + (size_t)b * 1024 * 1024;
    u16* ho = hout + (size_t)b * 1024 * 256;
    __syncthreads();

    float pcur[4], pnext[4];
    #pragma unroll
    for (int g = 0; g < 4; ++g) pcur[g] = (float)prep_[g * 256 + j];

    for (int t = 0; t < 1024; ++t) {
        int tn = (t + 1 < 1024) ? (t + 1) : 1023;
        const f16* pn = prep_ + (size_t)tn * 1024;
        #pragma unroll
        for (int g = 0; g < 4; ++g) pnext[g] = (float)pn[g * 256 + j];

        const f16x8* hrow = (const f16x8*)(hsh + (t & 1) * 256);
        float z0 = pcur[0], z1 = pcur[1], z2 = pcur[2], z3 = pcur[3];
        f16x8 hq[8];

        // ---- quarter 0: pairs 0..31 (VGPR) ----
        #pragma unroll
        for (int r = 0; r < 8; ++r) hq[r] = hrow[r];
        #pragma unroll
        for (int k = 0; k < 32; ++k) {
            f16x2 hp = pair_of(hq[k >> 2], k & 3);
            z0 = fdot2(hp, ulr[0][k], z0);
            z1 = fdot2(hp, ulr[1][k], z1);
            z2 = fdot2(hp, ulr[2][k], z2);
            z3 = fdot2(hp, ulr[3][k], z3);
        }
        // ---- quarter 1: pairs 32..63 (VGPR 32..39, AGPR ka 0..23) ----
        #pragma unroll
        for (int r = 0; r < 8; ++r) hq[r] = hrow[8 + r];
        #pragma unroll
        for (int k = 32; k < 40; ++k) {
            f16x2 hp = pair_of(hq[(k - 32) >> 2], k & 3);
            z0 = fdot2(hp, ulr[0][k], z0);
            z1 = fdot2(hp, ulr[1][k], z1);
            z2 = fdot2(hp, ulr[2][k], z2);
            z3 = fdot2(hp, ulr[3][k], z3);
        }
        #pragma unroll
        for (int ka = 0; ka < 24; ++ka) {
            int k = 40 + ka;
            f16x2 hp = pair_of(hq[(k - 32) >> 2], k & 3);
            z0 = fdot2(hp, aread(agv[0 * RKA + ka]), z0);
            z1 = fdot2(hp, aread(agv[1 * RKA + ka]), z1);
            z2 = fdot2(hp, aread(agv[2 * RKA + ka]), z2);
            z3 = fdot2(hp, aread(agv[3 * RKA + ka]), z3);
        }
        // ---- quarter 2: pairs 64..95 (AGPR ka 24..55) ----
        #pragma unroll
        for (int r = 0; r < 8; ++r) hq[r] = hrow[16 + r];
        #pragma unroll
        for (int ka = 24; ka < 56; ++ka) {
            int k = 40 + ka;
            f16x2 hp = pair_of(hq[(k - 64) >> 2], k & 3);
            z0 = fdot2(hp, aread(agv[0 * RKA + ka]), z0);
            z1 = fdot2(hp, aread(agv[1 * RKA + ka]), z1);
            z2 = fdot2(hp, aread(agv[2 * RKA + ka]), z2);
            z3 = fdot2(hp, aread(agv[3 * RKA + ka]), z3);
        }
        // ---- quarter 3: pairs 96..127 (AGPR ka 56..63, LDS 104..127) ----
        #pragma unroll
        for (int r = 0; r < 8; ++r) hq[r] = hrow[24 + r];
        #pragma unroll
        for (int ka = 56; ka < 64; ++ka) {
            int k = 40 + ka;
            f16x2 hp = pair_of(hq[(k - 96) >> 2], k & 3);
            z0 = fdot2(hp, aread(agv[0 * RKA + ka]), z0);
            z1 = fdot2(hp, aread(agv[1 * RKA + ka]), z1);
            z2 = fdot2(hp, aread(agv[2 * RKA + ka]), z2);
            z3 = fdot2(hp, aread(agv[3 * RKA + ka]), z3);
        }
        #pragma unroll
        for (int kc = 0; kc < RKL / 4; ++kc) {
            f16x8 w0 = wlds[(kc * 4 + 0) * 256 + j];
            f16x8 w1 = wlds[(kc * 4 + 1) * 256 + j];
            f16x8 w2 = wlds[(kc * 4 + 2) * 256 + j];
            f16x8 w3 = wlds[(kc * 4 + 3) * 256 + j];
            #pragma unroll
            for (int p = 0; p < 4; ++p) {
                int k = 104 + kc * 4 + p;
                f16x2 hp = pair_of(hq[(k - 96) >> 2], k & 3);
                z0 = fdot2(hp, pair_of(w0, p), z0);
                z1 = fdot2(hp, pair_of(w1, p), z1);
                z2 = fdot2(hp, pair_of(w2, p), z2);
                z3 = fdot2(hp, pair_of(w3, p), z3);
            }
        }
        // gates
        float ig = sigm(z0);
        float fg = sigm(z1);
        float gg = fast_tanh(z2);
        float og = sigm(z3);
        c = fg * c + ig * gg;
        float h = og * fast_tanh(c);
        hsh[((t + 1) & 1) * 256 + j] = (f16)h;
        ho[(size_t)t * 256 + j] = f2bf(h);
        #pragma unroll
        for (int g = 0; g < 4; ++g) pcur[g] = pnext[g];
        __syncthreads();
    }
}

// ---------------------------------------------------------------------------
// out[row] = sum_n sigmoid(h[row]@Wo[:,n] + bo[n]) * q[row,n]
// ---------------------------------------------------------------------------
__global__ __launch_bounds__(256) void gemm_out(const u16* __restrict__ H,
                                                const u16* __restrict__ woT,
                                                const float* __restrict__ bo,
                                                const float* __restrict__ q,
                                                float* __restrict__ out)
{
    __shared__ u16 Alds[64 * 40];
    __shared__ u16 Blds[256 * 40];
    __shared__ float red[64][4];
    int tid = threadIdx.x;
    int m0 = blockIdx.x * 64;
    int lane = tid & 63, w = tid >> 6, quad = lane >> 4, m16 = lane & 15;
    f4v acc[4][4];
    #pragma unroll
    for (int i = 0; i < 4; ++i)
        #pragma unroll
        for (int j = 0; j < 4; ++j) acc[i][j] = (f4v){0.f, 0.f, 0.f, 0.f};

    for (int k0 = 0; k0 < 256; k0 += 32) {
        {
            int e = tid * 8;
            int r = e >> 5, cc = e & 31;
            *(uint4*)&Alds[r * 40 + cc] =
                *(const uint4*)&H[(size_t)(m0 + r) * 256 + k0 + cc];
        }
        #pragma unroll
        for (int p = 0; p < 4; ++p) {
            int e = (p * 256 + tid) * 8;
            int r = e >> 5, cc = e & 31;
            *(uint4*)&Blds[r * 40 + cc] =
                *(const uint4*)&woT[(size_t)r * 256 + k0 + cc];
        }
        __syncthreads();
        s8v af[4], bf[4];
        #pragma unroll
        for (int i = 0; i < 4; ++i)
            af[i] = *(const s8v*)&Alds[(i * 16 + m16) * 40 + quad * 8];
        #pragma unroll
        for (int i = 0; i < 4; ++i)
            bf[i] = *(const s8v*)&Blds[(w * 64 + i * 16 + m16) * 40 + quad * 8];
        #pragma unroll
        for (int i = 0; i < 4; ++i)
            #pragma unroll
            for (int nj = 0; nj < 4; ++nj)
                acc[i][nj] = __builtin_amdgcn_mfma_f32_16x16x32_bf16(
                    af[i], bf[nj], acc[i][nj], 0, 0, 0);
        __syncthreads();
    }
    float rsum[4][4];
    #pragma unroll
    for (int i = 0; i < 4; ++i)
        #pragma unroll
        for (int r = 0; r < 4; ++r) rsum[i][r] = 0.f;
    #pragma unroll
    for (int nj = 0; nj < 4; ++nj) {
        int col = w * 64 + nj * 16 + m16;
        float bv = bo[col];
        #pragma unroll
        for (int i = 0; i < 4; ++i)
            #pragma unroll
            for (int r = 0; r < 4; ++r) {
                int row = m0 + i * 16 + quad * 4 + r;
                float v = sigm(acc[i][nj][r] + bv);
                rsum[i][r] += v * q[(size_t)row * 256 + col];
            }
    }
    #pragma unroll
    for (int d = 1; d <= 8; d <<= 1)
        #pragma unroll
        for (int i = 0; i < 4; ++i)
            #pragma unroll
            for (int r = 0; r < 4; ++r) rsum[i][r] += __shfl_xor(rsum[i][r], d);
    if (m16 == 0) {
        #pragma unroll
        for (int i = 0; i < 4; ++i)
            #pragma unroll
            for (int r = 0; r < 4; ++r)
                red[i * 16 + quad * 4 + r][w] = rsum[i][r];
    }
    __syncthreads();
    if (tid < 64)
        out[m0 + tid] = red[tid][0] + red[tid][1] + red[tid][2] + red[tid][3];
}

// ---------------------------------------------------------------------------
extern "C" void kernel_launch(void* const* d_in, const int* in_sizes, int n_in,
                              void* d_out, int out_size, void* d_ws, size_t ws_size,
                              hipStream_t stream)
{
    (void)in_sizes; (void)n_in; (void)out_size; (void)ws_size;
    const float* x     = (const float*)d_in[0];
    const float* delta = (const float*)d_in[1];
    const float* q     = (const float*)d_in[2];
    const float* Wx    = (const float*)d_in[3];
    const float* bx    = (const float*)d_in[4];
    const float* Wc    = (const float*)d_in[5];
    const float* bc    = (const float*)d_in[6];
    const float* Wd    = (const float*)d_in[7];
    const float* bd    = (const float*)d_in[8];
    const float* Wl    = (const float*)d_in[9];
    const float* Ul    = (const float*)d_in[10];
    const float* bl    = (const float*)d_in[11];
    const float* Wo    = (const float*)d_in[12];
    const float* bo    = (const float*)d_in[13];

    char* ws = (char*)d_ws;
    float* s_buf = (float*)(ws + 0);            // 256 KB
    f16x2* ull   = (f16x2*)(ws + 262144);       // 512 KB
    u16* wxT     = (u16*)(ws + 786432);         // 128 KB
    u16* wcT     = (u16*)(ws + 917504);         // 128 KB
    u16* wlT     = (u16*)(ws + 1048576);        // 576 KB
    u16* woT     = (u16*)(ws + 1638400);        // 128 KB
    u16* xc      = (u16*)(ws + 1769472);        // 36 MB  [65536 x 288] bf16
    u16* hbuf    = (u16*)(ws + 39518208);       // 32 MB  [65536 x 256] bf16
    u16* xbf     = (u16*)(ws + 73072640);       // 64 MB  bf16 copy of x
    u16* clog    = (u16*)(ws + 140181504);      // 64 MB  log1p(counts) bf16
    f16* pre     = (f16*)(ws + 73072640);       // 128 MB f16, aliases xbf+clog

    // allow >64KB dynamic LDS for the LSTM kernel (gfx950: 160 KB/WG)
    hipFuncSetAttribute((const void*)lstm_kernel,
                        hipFuncAttributeMaxDynamicSharedMemorySize, LSTM_SMEM);

    prep_kernel<<<2432, 256, 0, stream>>>(Wx, Wc, Wl, Wo, Ul, wxT, wcT, wlT, woT, ull);
    row_sums<<<16384, 256, 0, stream>>>((const float4*)x, s_buf);
    count_scan<<<64, 512, 0, stream>>>(x, s_buf, xbf, clog);
    fill_xc<<<8192, 256, 0, stream>>>(delta, Wd, bd, xc);
    gemm128<0><<<dim3(512, 1), 256, 0, stream>>>(xbf, wxT, bx, xc, 512, 288, 0);
    gemm128<0><<<dim3(512, 1), 256, 0, stream>>>(clog, wcT, bc, xc, 512, 288, 128);
    gemm128<1><<<dim3(512, 8), 256, 0, stream>>>(xc, wlT, bl, (u16*)pre, 288, 1024, 0);
    lstm_kernel<<<64, 256, LSTM_SMEM, stream>>>(pre, ull, hbuf);
    gemm_out<<<1024, 256, 0, stream>>>(hbuf, woT, bo, q, (float*)d_out);
}

// Round 4
// 3140.236 us; speedup vs baseline: 4.8720x; 1.0840x over previous
//
#include <hip/hip_runtime.h>
#include <hip/hip_bf16.h>

typedef unsigned short u16;
typedef _Float16 f16;
typedef _Float16 f16x2 __attribute__((ext_vector_type(2)));
typedef _Float16 f16x8 __attribute__((ext_vector_type(8)));
typedef short s8v __attribute__((ext_vector_type(8)));
typedef float f4v __attribute__((ext_vector_type(4)));

// LSTM Ul residency split (128 k-pairs total): VGPR + AGPR + LDS, all CU-resident
#define RKV 28                          // pairs in VGPRs (4 x 28 = 112 regs)
#define RKA 64                          // pairs in AGPRs (4 x 64 = 256 AGPRs)
#define RKL 36                          // pairs in LDS   (144 KB)
#define NLC 9                           // RKL/4 chunks
#define AOFF (4 * RKV * 256)            // 28672 pairs
#define LOFF (AOFF + 4 * RKA * 256)     // 94208 pairs
#define WLDS_BYTES (NLC * 4 * 256 * 16) // 147456
#define LSTM_SMEM (WLDS_BYTES + 2 * 256 * 2)  // + h double buffer = 148480

__device__ __forceinline__ u16 f2bf(float f) {
    union { float f; unsigned u; } v; v.f = f;
    unsigned r = v.u + 0x7FFF + ((v.u >> 16) & 1);
    return (u16)(r >> 16);
}
__device__ __forceinline__ u16 f2h(float f) {
    f16 h = (f16)f;
    union { f16 h; u16 u; } v; v.h = h;
    return v.u;
}
__device__ __forceinline__ f16x2 pair_of(f16x8 v, int i) {
    union { f16x8 v8; f16x2 p[4]; } u; u.v8 = v;
    return u.p[i];
}
__device__ __forceinline__ float fdot2(f16x2 a, f16x2 b, float c) {
#if defined(__has_builtin) && __has_builtin(__builtin_amdgcn_fdot2)
    return __builtin_amdgcn_fdot2(a, b, c, false);
#else
    return c + (float)a.x * (float)b.x + (float)a.y * (float)b.y;
#endif
}
__device__ __forceinline__ float sigm(float x) { return 1.f / (1.f + __expf(-x)); }
__device__ __forceinline__ float fast_tanh(float x) {
    float ax = fabsf(x);
    float e = __expf(2.f * ax);
    float r = 1.f - 2.f / (e + 1.f);   // overflow-safe: e=inf -> r=1
    return copysignf(r, x);
}
__device__ __forceinline__ f16x2 aread(const float& a) {
    union { float f; f16x2 p; } u;
    asm volatile("v_accvgpr_read_b32 %0, %1" : "=v"(u.f) : "a"(a));
    return u.p;
}

// ---------------------------------------------------------------------------
// Weight prep: transposes to [N][K] bf16 for MFMA B-operand, packs Ul to f16
// pair layout for the LSTM: VGPR region / AGPR region / LDS region.
// ---------------------------------------------------------------------------
__global__ __launch_bounds__(256) void prep_kernel(
    const float* __restrict__ Wx, const float* __restrict__ Wc,
    const float* __restrict__ Wl, const float* __restrict__ Wo,
    const float* __restrict__ Ul,
    u16* __restrict__ wxT, u16* __restrict__ wcT, u16* __restrict__ wlT,
    u16* __restrict__ woT, f16x2* __restrict__ ull)
{
    int i = blockIdx.x * 256 + threadIdx.x;
    if (i < 65536) {                    // WxT[n][k] : 128x512
        int n = i >> 9, k = i & 511;
        wxT[i] = f2bf(Wx[k * 128 + n]);
    } else if (i < 131072) {            // WcT
        int t = i - 65536;
        int n = t >> 9, k = t & 511;
        wcT[t] = f2bf(Wc[k * 128 + n]);
    } else if (i < 425984) {            // WlT[n][k] : 1024x288 (K padded 257->288)
        int t = i - 131072;
        int n = t / 288, k = t % 288;
        wlT[t] = (k < 257) ? f2bf(Wl[k * 1024 + n]) : (u16)0;
    } else if (i < 491520) {            // WoT[n][k] : 256x256
        int t = i - 425984;
        int n = t >> 8, k = t & 255;
        woT[t] = f2bf(Wo[k * 256 + n]);
    } else if (i < 622592) {            // Ul packed f16 pairs: 131072 pairs
        int t = i - 491520;
        int j = t & 255;
        int r = t >> 8;                 // [0,512)
        int k2 = r & 127;               // global pair index
        int g = r >> 7;                 // gate
        int outi;
        if (k2 < RKV) {
            outi = (g * RKV + k2) * 256 + j;
        } else if (k2 < RKV + RKA) {
            outi = AOFF + (g * RKA + (k2 - RKV)) * 256 + j;
        } else {
            int kl = k2 - RKV - RKA;    // [0,RKL)
            int kc = kl >> 2, p = kl & 3;
            outi = LOFF + ((kc * 4 + g) * 256 + j) * 4 + p;
        }
        int col = g * 256 + j;
        f16x2 v;
        v.x = (f16)Ul[(2 * k2) * 1024 + col];
        v.y = (f16)Ul[(2 * k2 + 1) * 1024 + col];
        ull[outi] = v;
    }
}

// ---------------------------------------------------------------------------
// s[b,t] = sum_k x[b,t,k]   (one wave per row)
// ---------------------------------------------------------------------------
__global__ __launch_bounds__(256) void row_sums(const float4* __restrict__ x4,
                                                float* __restrict__ s)
{
    int w = threadIdx.x >> 6, lane = threadIdx.x & 63;
    size_t row = (size_t)blockIdx.x * 4 + w;
    const float4* r = x4 + row * 128;
    float4 a = r[lane], b = r[64 + lane];
    float sum = a.x + a.y + a.z + a.w + b.x + b.y + b.z + b.w;
    #pragma unroll
    for (int d = 32; d >= 1; d >>= 1) sum += __shfl_xor(sum, d);
    if (lane == 0) s[row] = sum;
}

// ---------------------------------------------------------------------------
// Count recurrence, 3-phase chunked (8 chunks of 128 steps per batch):
// A: per-chunk zero-init scan -> cend, P=prod(s).  B: combine chunk heads.
// C: re-scan with true c_in, write bf16 x and log1p(count).
// ---------------------------------------------------------------------------
__global__ __launch_bounds__(512) void count_phaseA(const float* __restrict__ x,
                                                    const float* __restrict__ s,
                                                    float* __restrict__ cend,
                                                    float* __restrict__ Pq)
{
    int k = threadIdx.x, bi = blockIdx.x;
    int b = bi >> 3, qc = bi & 7;
    const float* xb = x + ((size_t)b * 1024 + qc * 128) * 512;
    const float* sb = s + b * 1024 + qc * 128;
    float c = 0.f, P = 1.f;
    for (int t0 = 0; t0 < 128; t0 += 8) {
        float xv[8], sv[8];
        #pragma unroll
        for (int i = 0; i < 8; ++i) {
            xv[i] = xb[(size_t)(t0 + i) * 512 + k];
            sv[i] = sb[t0 + i];
        }
        #pragma unroll
        for (int i = 0; i < 8; ++i) { c = sv[i] * c + xv[i]; P *= sv[i]; }
    }
    cend[(size_t)bi * 512 + k] = c;
    if (k == 0) Pq[bi] = P;
}

__global__ __launch_bounds__(512) void count_phaseB(const float* __restrict__ cend,
                                                    const float* __restrict__ Pq,
                                                    float* __restrict__ cin)
{
    int k = threadIdx.x, b = blockIdx.x;
    float c = 0.f;
    for (int q = 0; q < 8; ++q) {
        int bi = b * 8 + q;
        cin[(size_t)bi * 512 + k] = c;
        c = Pq[bi] * c + cend[(size_t)bi * 512 + k];
    }
}

__global__ __launch_bounds__(512) void count_phaseC(const float* __restrict__ x,
                                                    const float* __restrict__ s,
                                                    const float* __restrict__ cin,
                                                    u16* __restrict__ xbf,
                                                    u16* __restrict__ clog)
{
    int k = threadIdx.x, bi = blockIdx.x;
    int b = bi >> 3, qc = bi & 7;
    size_t base = ((size_t)b * 1024 + qc * 128) * 512;
    const float* xb = x + base;
    const float* sb = s + b * 1024 + qc * 128;
    u16* xo = xbf + base;
    u16* co = clog + base;
    float c = cin[(size_t)bi * 512 + k];
    for (int t0 = 0; t0 < 128; t0 += 8) {
        float xv[8], sv[8];
        #pragma unroll
        for (int i = 0; i < 8; ++i) {
            xv[i] = xb[(size_t)(t0 + i) * 512 + k];
            sv[i] = sb[t0 + i];
        }
        #pragma unroll
        for (int i = 0; i < 8; ++i) {
            c = sv[i] * c + xv[i];
            size_t idx = (size_t)(t0 + i) * 512 + k;
            xo[idx] = f2bf(xv[i]);
            co[idx] = f2bf(log1pf(c));
        }
    }
}

// ---------------------------------------------------------------------------
// xc[:,256] = exp(-(delta*Wd+bd)); xc[:,257:288] = 0
// ---------------------------------------------------------------------------
__global__ __launch_bounds__(256) void fill_xc(const float* __restrict__ delta,
                                               const float* __restrict__ Wd,
                                               const float* __restrict__ bd,
                                               u16* __restrict__ xc)
{
    int i = blockIdx.x * 256 + threadIdx.x;   // 65536*32
    int row = i >> 5, cc = i & 31;
    float v = 0.f;
    if (cc == 0) v = __expf(-(delta[row] * Wd[0] + bd[0]));
    xc[(size_t)row * 288 + 256 + cc] = f2bf(v);
}

// ---------------------------------------------------------------------------
// Generic 128x128-tile bf16 MFMA GEMM: C[row, colofs+col] = A@B + bias.
// ---------------------------------------------------------------------------
template <int EPI>
__global__ __launch_bounds__(256) void gemm128(const u16* __restrict__ A,
                                               const u16* __restrict__ BT,
                                               const float* __restrict__ bias,
                                               u16* __restrict__ C,
                                               int K, int ldc, int colofs)
{
    __shared__ u16 Alds[128 * 40];
    __shared__ u16 Blds[128 * 40];
    int tid = threadIdx.x;
    int m0 = blockIdx.x * 128, n0 = blockIdx.y * 128;
    int lane = tid & 63, w = tid >> 6, quad = lane >> 4, m16 = lane & 15;
    int wm = w & 1, wn = w >> 1;
    f4v acc[4][4];
    #pragma unroll
    for (int i = 0; i < 4; ++i)
        #pragma unroll
        for (int j = 0; j < 4; ++j) acc[i][j] = (f4v){0.f, 0.f, 0.f, 0.f};

    for (int k0 = 0; k0 < K; k0 += 32) {
        #pragma unroll
        for (int p = 0; p < 2; ++p) {
            int e = (p * 256 + tid) * 8;
            int r = e >> 5, cc = e & 31;
            *(uint4*)&Alds[r * 40 + cc] =
                *(const uint4*)&A[(size_t)(m0 + r) * K + k0 + cc];
            *(uint4*)&Blds[r * 40 + cc] =
                *(const uint4*)&BT[(size_t)(n0 + r) * K + k0 + cc];
        }
        __syncthreads();
        s8v af[4], bf[4];
        #pragma unroll
        for (int i = 0; i < 4; ++i)
            af[i] = *(const s8v*)&Alds[(wm * 64 + i * 16 + m16) * 40 + quad * 8];
        #pragma unroll
        for (int i = 0; i < 4; ++i)
            bf[i] = *(const s8v*)&Blds[(wn * 64 + i * 16 + m16) * 40 + quad * 8];
        #pragma unroll
        for (int i = 0; i < 4; ++i)
            #pragma unroll
            for (int nj = 0; nj < 4; ++nj)
                acc[i][nj] = __builtin_amdgcn_mfma_f32_16x16x32_bf16(
                    af[i], bf[nj], acc[i][nj], 0, 0, 0);
        __syncthreads();
    }
    #pragma unroll
    for (int nj = 0; nj < 4; ++nj) {
        int col = n0 + wn * 64 + nj * 16 + m16;
        float bv = bias[col];
        #pragma unroll
        for (int i = 0; i < 4; ++i)
            #pragma unroll
            for (int r = 0; r < 4; ++r) {
                int row = m0 + wm * 64 + i * 16 + quad * 4 + r;
                float v = acc[i][nj][r] + bv;
                C[(size_t)row * ldc + colofs + col] = (EPI == 0) ? f2bf(v) : f2h(v);
            }
    }
}

// ---------------------------------------------------------------------------
// LSTM over T=1024. One block per batch, 256 threads, 1 wave/SIMD.
// Ul fully CU-resident: 28 VGPR + 64 AGPR + 36 LDS pairs. All operand
// streams software-pipelined: h quarters double-buffered, AGPR reads
// prefetched 2 pairs ahead, LDS weight chunks prefetched 2 chunks ahead.
// ---------------------------------------------------------------------------
__global__ __launch_bounds__(256, 1) void lstm_kernel(const f16* __restrict__ pre,
                                                      const f16x2* __restrict__ ull,
                                                      u16* __restrict__ hout)
{
    extern __shared__ char smem[];
    f16x8* wlds = (f16x8*)smem;                       // [(kc*4+g)*256 + j]
    f16* hsh = (f16*)(smem + WLDS_BYTES);             // [2][256]
    int j = threadIdx.x, b = blockIdx.x;

    // stage LDS-resident weights (once)
    const f16x8* wl = (const f16x8*)(ull + LOFF);
    #pragma unroll
    for (int i = 0; i < NLC * 4; ++i)
        wlds[i * 256 + j] = wl[i * 256 + j];

    // VGPR-resident weights
    f16x2 ulr[4][RKV];
    #pragma unroll
    for (int g = 0; g < 4; ++g)
        #pragma unroll
        for (int k = 0; k < RKV; ++k)
            ulr[g][k] = ull[(g * RKV + k) * 256 + j];

    // AGPR-resident weights
    float agv[4 * RKA];
    {
        const f16x2* ua = ull + AOFF;
        #pragma unroll
        for (int i = 0; i < 4 * RKA; ++i) {
            union { f16x2 p; float f; } u;
            u.p = ua[i * 256 + j];
            asm volatile("v_accvgpr_write_b32 %0, %1" : "=a"(agv[i]) : "v"(u.f));
        }
    }

    float c = 0.f;
    hsh[j] = (f16)0.f;
    const f16* prep_ = pre + (size_t)b * 1024 * 1024;
    u16* ho = hout + (size_t)b * 1024 * 256;
    __syncthreads();

    float pcur[4], pnext[4];
    #pragma unroll
    for (int g = 0; g < 4; ++g) pcur[g] = (float)prep_[g * 256 + j];

    for (int t = 0; t < 1024; ++t) {
        int tn = (t + 1 < 1024) ? (t + 1) : 1023;
        const f16* pn = prep_ + (size_t)tn * 1024;
        #pragma unroll
        for (int g = 0; g < 4; ++g) pnext[g] = (float)pn[g * 256 + j];

        const f16x8* hrow = (const f16x8*)(hsh + (t & 1) * 256);
        f16x8 hA[8], hB[8];
        #pragma unroll
        for (int r = 0; r < 8; ++r) hA[r] = hrow[r];        // Q0
        #pragma unroll
        for (int r = 0; r < 8; ++r) hB[r] = hrow[8 + r];    // prefetch Q1

        float z0 = pcur[0], z1 = pcur[1], z2 = pcur[2], z3 = pcur[3];

        // AGPR prefetch buffer (2 pairs deep)
        f16x2 ab[2][4];
        #pragma unroll
        for (int g = 0; g < 4; ++g) ab[0][g] = aread(agv[g * RKA + 0]);
        #pragma unroll
        for (int g = 0; g < 4; ++g) ab[1][g] = aread(agv[g * RKA + 1]);

        // ---- Q0: k 0..31 (VGPR 0..27, AGPR ka 0..3), h in hA ----
        #pragma unroll
        for (int k = 0; k < 32; ++k) {
            f16x2 hp = pair_of(hA[k >> 2], k & 3);
            if (k < RKV) {
                z0 = fdot2(hp, ulr[0][k], z0);
                z1 = fdot2(hp, ulr[1][k], z1);
                z2 = fdot2(hp, ulr[2][k], z2);
                z3 = fdot2(hp, ulr[3][k], z3);
            } else {
                int ka = k - RKV;
                z0 = fdot2(hp, ab[ka & 1][0], z0);
                z1 = fdot2(hp, ab[ka & 1][1], z1);
                z2 = fdot2(hp, ab[ka & 1][2], z2);
                z3 = fdot2(hp, ab[ka & 1][3], z3);
                #pragma unroll
                for (int g = 0; g < 4; ++g)
                    ab[ka & 1][g] = aread(agv[g * RKA + ka + 2]);
            }
        }
        // ---- Q1: k 32..63 (AGPR ka 4..35), h in hB; prefetch Q2 into hA ----
        #pragma unroll
        for (int r = 0; r < 8; ++r) hA[r] = hrow[16 + r];
        #pragma unroll
        for (int ka = 4; ka < 36; ++ka) {
            int kk = ka + RKV - 32;      // h pair index within Q1
            f16x2 hp = pair_of(hB[kk >> 2], kk & 3);
            z0 = fdot2(hp, ab[ka & 1][0], z0);
            z1 = fdot2(hp, ab[ka & 1][1], z1);
            z2 = fdot2(hp, ab[ka & 1][2], z2);
            z3 = fdot2(hp, ab[ka & 1][3], z3);
            if (ka + 2 < RKA) {
                #pragma unroll
                for (int g = 0; g < 4; ++g)
                    ab[ka & 1][g] = aread(agv[g * RKA + ka + 2]);
            }
        }
        // ---- Q2: k 64..95 (AGPR ka 36..63, LDS chunk 0), h in hA ----
        #pragma unroll
        for (int r = 0; r < 8; ++r) hB[r] = hrow[24 + r];   // prefetch Q3
        f16x8 wv[2][4];
        #pragma unroll
        for (int g = 0; g < 4; ++g) wv[0][g] = wlds[(0 * 4 + g) * 256 + j];
        #pragma unroll
        for (int g = 0; g < 4; ++g) wv[1][g] = wlds[(1 * 4 + g) * 256 + j];
        #pragma unroll
        for (int ka = 36; ka < 64; ++ka) {
            int kk = ka + RKV - 64;      // h pair index within Q2
            f16x2 hp = pair_of(hA[kk >> 2], kk & 3);
            z0 = fdot2(hp, ab[ka & 1][0], z0);
            z1 = fdot2(hp, ab[ka & 1][1], z1);
            z2 = fdot2(hp, ab[ka & 1][2], z2);
            z3 = fdot2(hp, ab[ka & 1][3], z3);
            if (ka + 2 < RKA) {
                #pragma unroll
                for (int g = 0; g < 4; ++g)
                    ab[ka & 1][g] = aread(agv[g * RKA + ka + 2]);
            }
        }
        // ---- LDS region: k 92..127 in 9 chunks of 4 pairs ----
        #pragma unroll
        for (int kc = 0; kc < NLC; ++kc) {
            f16x8 w0 = wv[kc & 1][0], w1 = wv[kc & 1][1];
            f16x8 w2 = wv[kc & 1][2], w3 = wv[kc & 1][3];
            if (kc + 2 < NLC) {
                #pragma unroll
                for (int g = 0; g < 4; ++g)
                    wv[kc & 1][g] = wlds[((kc + 2) * 4 + g) * 256 + j];
            }
            #pragma unroll
            for (int p = 0; p < 4; ++p) {
                // chunk 0 = k 92..95 (Q2/hA tail pair idx 28..31); kc>=1 in hB
                f16x2 hp = (kc == 0) ? pair_of(hA[7], p) : pair_of(hB[kc - 1], p);
                z0 = fdot2(hp, pair_of(w0, p), z0);
                z1 = fdot2(hp, pair_of(w1, p), z1);
                z2 = fdot2(hp, pair_of(w2, p), z2);
                z3 = fdot2(hp, pair_of(w3, p), z3);
            }
        }
        // gates
        float ig = sigm(z0);
        float fg = sigm(z1);
        float gg = fast_tanh(z2);
        float og = sigm(z3);
        c = fg * c + ig * gg;
        float h = og * fast_tanh(c);
        hsh[((t + 1) & 1) * 256 + j] = (f16)h;
        ho[(size_t)t * 256 + j] = f2bf(h);
        #pragma unroll
        for (int g = 0; g < 4; ++g) pcur[g] = pnext[g];
        __syncthreads();
    }
}

// ---------------------------------------------------------------------------
// out[row] = sum_n sigmoid(h[row]@Wo[:,n] + bo[n]) * q[row,n]
// ---------------------------------------------------------------------------
__global__ __launch_bounds__(256) void gemm_out(const u16* __restrict__ H,
                                                const u16* __restrict__ woT,
                                                const float* __restrict__ bo,
                                                const float* __restrict__ q,
                                                float* __restrict__ out)
{
    __shared__ u16 Alds[64 * 40];
    __shared__ u16 Blds[256 * 40];
    __shared__ float red[64][4];
    int tid = threadIdx.x;
    int m0 = blockIdx.x * 64;
    int lane = tid & 63, w = tid >> 6, quad = lane >> 4, m16 = lane & 15;
    f4v acc[4][4];
    #pragma unroll
    for (int i = 0; i < 4; ++i)
        #pragma unroll
        for (int j = 0; j < 4; ++j) acc[i][j] = (f4v){0.f, 0.f, 0.f, 0.f};

    for (int k0 = 0; k0 < 256; k0 += 32) {
        {
            int e = tid * 8;
            int r = e >> 5, cc = e & 31;
            *(uint4*)&Alds[r * 40 + cc] =
                *(const uint4*)&H[(size_t)(m0 + r) * 256 + k0 + cc];
        }
        #pragma unroll
        for (int p = 0; p < 4; ++p) {
            int e = (p * 256 + tid) * 8;
            int r = e >> 5, cc = e & 31;
            *(uint4*)&Blds[r * 40 + cc] =
                *(const uint4*)&woT[(size_t)r * 256 + k0 + cc];
        }
        __syncthreads();
        s8v af[4], bf[4];
        #pragma unroll
        for (int i = 0; i < 4; ++i)
            af[i] = *(const s8v*)&Alds[(i * 16 + m16) * 40 + quad * 8];
        #pragma unroll
        for (int i = 0; i < 4; ++i)
            bf[i] = *(const s8v*)&Blds[(w * 64 + i * 16 + m16) * 40 + quad * 8];
        #pragma unroll
        for (int i = 0; i < 4; ++i)
            #pragma unroll
            for (int nj = 0; nj < 4; ++nj)
                acc[i][nj] = __builtin_amdgcn_mfma_f32_16x16x32_bf16(
                    af[i], bf[nj], acc[i][nj], 0, 0, 0);
        __syncthreads();
    }
    float rsum[4][4];
    #pragma unroll
    for (int i = 0; i < 4; ++i)
        #pragma unroll
        for (int r = 0; r < 4; ++r) rsum[i][r] = 0.f;
    #pragma unroll
    for (int nj = 0; nj < 4; ++nj) {
        int col = w * 64 + nj * 16 + m16;
        float bv = bo[col];
        #pragma unroll
        for (int i = 0; i < 4; ++i)
            #pragma unroll
            for (int r = 0; r < 4; ++r) {
                int row = m0 + i * 16 + quad * 4 + r;
                float v = sigm(acc[i][nj][r] + bv);
                rsum[i][r] += v * q[(size_t)row * 256 + col];
            }
    }
    #pragma unroll
    for (int d = 1; d <= 8; d <<= 1)
        #pragma unroll
        for (int i = 0; i < 4; ++i)
            #pragma unroll
            for (int r = 0; r < 4; ++r) rsum[i][r] += __shfl_xor(rsum[i][r], d);
    if (m16 == 0) {
        #pragma unroll
        for (int i = 0; i < 4; ++i)
            #pragma unroll
            for (int r = 0; r < 4; ++r)
                red[i * 16 + quad * 4 + r][w] = rsum[i][r];
    }
    __syncthreads();
    if (tid < 64)
        out[m0 + tid] = red[tid][0] + red[tid][1] + red[tid][2] + red[tid][3];
}

// ---------------------------------------------------------------------------
extern "C" void kernel_launch(void* const* d_in, const int* in_sizes, int n_in,
                              void* d_out, int out_size, void* d_ws, size_t ws_size,
                              hipStream_t stream)
{
    (void)in_sizes; (void)n_in; (void)out_size; (void)ws_size;
    const float* x     = (const float*)d_in[0];
    const float* delta = (const float*)d_in[1];
    const float* q     = (const float*)d_in[2];
    const float* Wx    = (const float*)d_in[3];
    const float* bx    = (const float*)d_in[4];
    const float* Wc    = (const float*)d_in[5];
    const float* bc    = (const float*)d_in[6];
    const float* Wd    = (const float*)d_in[7];
    const float* bd    = (const float*)d_in[8];
    const float* Wl    = (const float*)d_in[9];
    const float* Ul    = (const float*)d_in[10];
    const float* bl    = (const float*)d_in[11];
    const float* Wo    = (const float*)d_in[12];
    const float* bo    = (const float*)d_in[13];

    char* ws = (char*)d_ws;
    float* s_buf = (float*)(ws + 0);            // 256 KB
    f16x2* ull   = (f16x2*)(ws + 262144);       // 512 KB
    u16* wxT     = (u16*)(ws + 786432);         // 128 KB
    u16* wcT     = (u16*)(ws + 917504);         // 128 KB
    u16* wlT     = (u16*)(ws + 1048576);        // 576 KB
    u16* woT     = (u16*)(ws + 1638400);        // 128 KB
    u16* xc      = (u16*)(ws + 1769472);        // 36 MB  [65536 x 288] bf16
    u16* hbuf    = (u16*)(ws + 39518208);       // 32 MB  [65536 x 256] bf16
    u16* xbf     = (u16*)(ws + 73072640);       // 64 MB  bf16 copy of x
    u16* clog    = (u16*)(ws + 140181504);      // 64 MB  log1p(counts) bf16
    f16* pre     = (f16*)(ws + 73072640);       // 128 MB f16, aliases xbf+clog
    // count-scan scratch lives in the (not yet used) hbuf region
    float* cend  = (float*)hbuf;                // 1 MB
    float* cin   = (float*)(ws + 39518208 + (1 << 20));   // 1 MB
    float* Pq    = (float*)(ws + 39518208 + (2 << 20));   // 2 KB

    // allow >64KB dynamic LDS for the LSTM kernel (gfx950: 160 KB/WG)
    hipFuncSetAttribute((const void*)lstm_kernel,
                        hipFuncAttributeMaxDynamicSharedMemorySize, LSTM_SMEM);

    prep_kernel<<<2432, 256, 0, stream>>>(Wx, Wc, Wl, Wo, Ul, wxT, wcT, wlT, woT, ull);
    row_sums<<<16384, 256, 0, stream>>>((const float4*)x, s_buf);
    count_phaseA<<<512, 512, 0, stream>>>(x, s_buf, cend, Pq);
    count_phaseB<<<64, 512, 0, stream>>>(cend, Pq, cin);
    count_phaseC<<<512, 512, 0, stream>>>(x, s_buf, cin, xbf, clog);
    fill_xc<<<8192, 256, 0, stream>>>(delta, Wd, bd, xc);
    gemm128<0><<<dim3(512, 1), 256, 0, stream>>>(xbf, wxT, bx, xc, 512, 288, 0);
    gemm128<0><<<dim3(512, 1), 256, 0, stream>>>(clog, wcT, bc, xc, 512, 288, 128);
    gemm128<1><<<dim3(512, 8), 256, 0, stream>>>(xc, wlT, bl, (u16*)pre, 288, 1024, 0);
    lstm_kernel<<<64, 256, LSTM_SMEM, stream>>>(pre, ull, hbuf);
    gemm_out<<<1024, 256, 0, stream>>>(hbuf, woT, bo, q, (float*)d_out);
}